// Round 4
// baseline (314.347 us; speedup 1.0000x reference)
//
#include <hip/hip_runtime.h>
#include <math.h>

#define BATCH 16384
#define INFEAT 256
#define HID 128
#define NQ 10
#define NL 4

// ---------- cross-lane xor helper: DPP for 1,2,3,8; ds_swizzle for <32; shfl for 32+ ----------
template<int M>
__device__ __forceinline__ float lxor(float x) {
    if constexpr (M == 0) {
        return x;
    } else if constexpr (M < 4) {
        constexpr int ctrl = (0 ^ M) | ((1 ^ M) << 2) | ((2 ^ M) << 4) | ((3 ^ M) << 6);
        return __int_as_float(__builtin_amdgcn_update_dpp(
            __float_as_int(x), __float_as_int(x), ctrl, 0xF, 0xF, false));
    } else if constexpr (M == 8) {
        return __int_as_float(__builtin_amdgcn_update_dpp(
            __float_as_int(x), __float_as_int(x), 0x128, 0xF, 0xF, false));  // ROW_ROR:8
    } else if constexpr (M < 32) {
        return __int_as_float(__builtin_amdgcn_ds_swizzle(
            __float_as_int(x), (M << 10) | 0x1F));
    } else {
        return __shfl_xor(x, M, 64);
    }
}

__device__ __forceinline__ float wave_sum(float v) {
    v += lxor<1>(v); v += lxor<2>(v); v += lxor<8>(v);
    v += lxor<4>(v); v += lxor<16>(v); v += lxor<32>(v);
    return v;
}

// gfx950 VALU cross-lane exchange: a[hi-part] <-> b[lo-part] at 16/32-lane granularity
template<int HALF>
__device__ __forceinline__ void swap_pl(float& a, float& b) {
    if constexpr (HALF == 32)
        asm("v_permlane32_swap_b32 %0, %1" : "+v"(a), "+v"(b));
    else
        asm("v_permlane16_swap_b32 %0, %1" : "+v"(a), "+v"(b));
}

// lane-bit Rot gate at 16/32-lane granularity via permlane swaps (pure VALU).
// swap(A,B) -> X holds side-0 rows of both regs, Y holds side-1 rows.
// P = m00*X + m01*Y (all new side-0 values), Q = m10*X + m11*Y; swap(P,Q) -> (newA, newB).
template<int HALF>
__device__ __forceinline__ void lane_gate_pl(const float* __restrict__ g,
                                             float (&are)[16], float (&aim)[16]) {
    const float m00r = g[0], m00i = g[1], m01r = g[2], m01i = g[3];
    const float m10r = g[4], m10i = g[5], m11r = g[6], m11i = g[7];
#pragma unroll
    for (int r0 = 0; r0 < 16; r0 += 2) {
        const int r1 = r0 + 1;
        float Xr = are[r0], Yr = are[r1], Xi = aim[r0], Yi = aim[r1];
        swap_pl<HALF>(Xr, Yr);
        swap_pl<HALF>(Xi, Yi);
        float Pr = m00r * Xr - m00i * Xi + m01r * Yr - m01i * Yi;
        float Pi = m00r * Xi + m00i * Xr + m01r * Yi + m01i * Yr;
        float Qr = m10r * Xr - m10i * Xi + m11r * Yr - m11i * Yi;
        float Qi = m10r * Xi + m10i * Xr + m11r * Yi + m11i * Yr;
        swap_pl<HALF>(Pr, Qr);
        swap_pl<HALF>(Pi, Qi);
        are[r0] = Pr; are[r1] = Qr; aim[r0] = Pi; aim[r1] = Qi;
    }
}

// lane-bit Rot gate via lxor partner (DPP for bits 0,1,3; swizzle for bit 2)
template<int LB>
__device__ __forceinline__ void lane_gate(const float* __restrict__ g, int lane,
                                          float (&are)[16], float (&aim)[16]) {
    const bool side = (lane >> LB) & 1;
    const float cmr = side ? g[6] : g[0];
    const float cmi = side ? g[7] : g[1];
    const float cpr = side ? g[4] : g[2];
    const float cpi = side ? g[5] : g[3];
#pragma unroll
    for (int r = 0; r < 16; ++r) {
        float pr = lxor<(1 << LB)>(are[r]);
        float pi = lxor<(1 << LB)>(aim[r]);
        float nr = cmr * are[r] - cmi * aim[r] + cpr * pr - cpi * pi;
        float ni = cmr * aim[r] + cmi * are[r] + cpr * pi + cpi * pr;
        are[r] = nr; aim[r] = ni;
    }
}

// reg-bit Rot gate (reg-index bit mask)
template<int MASK>
__device__ __forceinline__ void reg_gate(const float* __restrict__ g,
                                         float (&are)[16], float (&aim)[16]) {
    const float m00r = g[0], m00i = g[1], m01r = g[2], m01i = g[3];
    const float m10r = g[4], m10i = g[5], m11r = g[6], m11i = g[7];
#pragma unroll
    for (int r0 = 0; r0 < 16; ++r0) {
        if (r0 & MASK) continue;
        const int r1 = r0 | MASK;
        float a0r = are[r0], a0i = aim[r0], a1r = are[r1], a1i = aim[r1];
        are[r0] = m00r * a0r - m00i * a0i + m01r * a1r - m01i * a1i;
        aim[r0] = m00r * a0i + m00i * a0r + m01r * a1i + m01i * a1r;
        are[r1] = m10r * a0r - m10i * a0i + m11r * a1r - m11i * a1i;
        aim[r1] = m10r * a0i + m10i * a0r + m11r * a1i + m11i * a1r;
    }
}

// ---- compile-time CNOT-ring tables ----
// RR gates (i=0..3-rs): reg-index permutation; gather needs pi^{-1} (reverse application)
constexpr int rr_src(int rs, int r) {
    int s = r;
    for (int i = 3 - rs; i >= 0; --i) s ^= ((s >> (3 - i)) & 1) << (3 - i - rs);
    return s;
}
// RL gates (i=max(0,4-rs)..3): per-reg lane xor mask
constexpr int rl_mask(int rs, int r) {
    int m = 0;
    for (int i = (4 - rs < 0 ? 0 : 4 - rs); i <= 3; ++i)
        if ((r >> (3 - i)) & 1) m |= 1 << (9 - i - rs);
    return m;
}

template<int L>
__device__ __forceinline__ void do_layer(const float* __restrict__ gt, int lane,
                                         float (&are)[16], float (&aim)[16]) {
    constexpr int rs = L + 1;
    const float* __restrict__ gb = gt + L * NQ * 8;
    // reg-bit Rot gates (qubits 0..3 -> reg bits 3..0)
    reg_gate<8>(gb + 0 * 8, are, aim);
    reg_gate<4>(gb + 1 * 8, are, aim);
    reg_gate<2>(gb + 2 * 8, are, aim);
    reg_gate<1>(gb + 3 * 8, are, aim);
    // lane-bit Rot gates (qubits 4..9 -> lane bits 5..0)
    lane_gate_pl<32>(gb + 4 * 8, are, aim);      // bit5: permlane32 swap
    lane_gate_pl<16>(gb + 5 * 8, are, aim);      // bit4: permlane16 swap
    lane_gate<3>(gb + 6 * 8, lane, are, aim);    // bit3: DPP row_ror:8
    lane_gate<2>(gb + 7 * 8, lane, are, aim);    // bit2: ds_swizzle
    lane_gate<1>(gb + 8 * 8, lane, are, aim);    // bit1: DPP
    lane_gate<0>(gb + 9 * 8, lane, are, aim);    // bit0: DPP
    // ---- CNOT ring: RR+RL+LL folded into one per-reg bpermute gather ----
    int y = lane;
#pragma unroll
    for (int i = 9 - rs; i >= 4; --i)
        y ^= ((y >> (9 - i)) & 1) << (9 - i - rs);   // LL inverse lane map
    const int base = y << 2;
    {
        float nr[16];
#pragma unroll
        for (int r = 0; r < 16; ++r) {
            constexpr int dummy = 0; (void)dummy;
            const int src = rr_src(rs, r);
            const int am  = rl_mask(rs, r) << 2;
            nr[r] = __int_as_float(__builtin_amdgcn_ds_bpermute(base ^ am, __float_as_int(are[src])));
        }
#pragma unroll
        for (int r = 0; r < 16; ++r) are[r] = nr[r];
    }
    {
        float ni[16];
#pragma unroll
        for (int r = 0; r < 16; ++r) {
            const int src = rr_src(rs, r);
            const int am  = rl_mask(rs, r) << 2;
            ni[r] = __int_as_float(__builtin_amdgcn_ds_bpermute(base ^ am, __float_as_int(aim[src])));
        }
#pragma unroll
        for (int r = 0; r < 16; ++r) aim[r] = ni[r];
    }
    // LR: ctrl lane bit 9-i, tgt reg bit 13-i-rs (after LL, lanes already permuted)
#pragma unroll
    for (int i = 10 - rs; i <= 9; ++i) {
        const bool p = (lane >> (9 - i)) & 1;
        const int tm = 1 << (13 - i - rs);
#pragma unroll
        for (int r = 0; r < 16; ++r) {
            if (!(r & tm)) {
                float v0r = are[r], v1r = are[r | tm];
                are[r] = p ? v1r : v0r;  are[r | tm] = p ? v0r : v1r;
                float v0i = aim[r], v1i = aim[r | tm];
                aim[r] = p ? v1i : v0i;  aim[r | tm] = p ? v0i : v1i;
            }
        }
    }
}

__device__ __forceinline__ float ftanh(float s) {
    float e = __expf(2.f * s);
    return 1.f - 2.f / (e + 1.f);
}

// ---------------- prep: gate table + W1 transpose ----------------
__global__ void prep_kernel(const float* __restrict__ qw, const float* __restrict__ W1,
                            float* __restrict__ gtab, float* __restrict__ w1t) {
    int tid = blockIdx.x * 256 + threadIdx.x;
    if (tid < INFEAT * HID) {
        int c = tid & 127, k = tid >> 7;
        w1t[k * HID + c] = W1[c * INFEAT + k];
    }
    if (blockIdx.x == 0 && threadIdx.x < NL * NQ) {
        int t = threadIdx.x;
        float phi = qw[t * 3 + 0], th = qw[t * 3 + 1], om = qw[t * 3 + 2];
        float c = __cosf(th * 0.5f), s = __sinf(th * 0.5f);
        float a = 0.5f * (phi + om), b = 0.5f * (phi - om);
        float ca = __cosf(a), sa = __sinf(a);
        float cb = __cosf(b), sb = __sinf(b);
        float* g = gtab + t * 8;
        g[0] = ca * c;  g[1] = -sa * c;
        g[2] = -cb * s; g[3] = -sb * s;
        g[4] = cb * s;  g[5] = -sb * s;
        g[6] = ca * c;  g[7] = sa * c;
    }
}

// ---------------- fused kernel: MLP -> circuit -> head, one wave per batch row ----------------
__global__ __launch_bounds__(256) void fused_kernel(
    const float* __restrict__ x, const float* __restrict__ w1t,
    const float* __restrict__ b1, const float* __restrict__ W2,
    const float* __restrict__ b2, const float* __restrict__ gtab,
    const float* __restrict__ W3, const float* __restrict__ b3,
    const float* __restrict__ W4, const float* __restrict__ b4,
    float* __restrict__ out)
{
    __shared__ float w3s[HID * 11];
    __shared__ float b3s[HID], w4s[HID];
    __shared__ float b4s;

    const int t = threadIdx.x;
    for (int f = t; f < HID * NQ; f += 256) {
        int c = f / NQ, k = f - c * NQ;
        w3s[c * 11 + k] = W3[f];
    }
    if (t < HID) { b3s[t] = b3[t]; w4s[t] = W4[t]; }
    if (t == 0) b4s = b4[0];
    __syncthreads();

    const int lane = t & 63;
    const int row = blockIdx.x * 4 + (t >> 6);
    const int urow = __builtin_amdgcn_readfirstlane(row);

    // ---- MLP: h = relu(x@W1^T+b1), lane owns cols 2*lane, 2*lane+1 ----
    const float4* __restrict__ xr4 = (const float4*)(x + (size_t)urow * INFEAT);  // uniform -> s_load
    const float2* __restrict__ w1c = (const float2*)w1t;                          // [k][64 float2]
    float acc0 = 0.f, acc1 = 0.f;
#pragma unroll 4
    for (int kk = 0; kk < 64; ++kk) {
        float4 xv = xr4[kk];
        float2 wa = w1c[(kk * 4 + 0) * 64 + lane];
        float2 wb = w1c[(kk * 4 + 1) * 64 + lane];
        float2 wc = w1c[(kk * 4 + 2) * 64 + lane];
        float2 wd = w1c[(kk * 4 + 3) * 64 + lane];
        acc0 = fmaf(xv.x, wa.x, acc0); acc1 = fmaf(xv.x, wa.y, acc1);
        acc0 = fmaf(xv.y, wb.x, acc0); acc1 = fmaf(xv.y, wb.y, acc1);
        acc0 = fmaf(xv.z, wc.x, acc0); acc1 = fmaf(xv.z, wc.y, acc1);
        acc0 = fmaf(xv.w, wd.x, acc0); acc1 = fmaf(xv.w, wd.y, acc1);
    }
    float2 b1v = ((const float2*)b1)[lane];
    float h0 = fmaxf(acc0 + b1v.x, 0.f);
    float h1 = fmaxf(acc1 + b1v.y, 0.f);

    // ---- angles = tanh(h@W2^T + b2), wave-reduced ----
    float cth[NQ], sth[NQ];
#pragma unroll
    for (int w = 0; w < NQ; ++w) {
        float2 w2v = ((const float2*)(W2 + (size_t)w * HID))[lane];
        float aw = wave_sum(fmaf(h0, w2v.x, h1 * w2v.y)) + b2[w];
        float th = ftanh(aw) * 0.5f;
        cth[w] = __cosf(th); sth[w] = __sinf(th);
    }

    // ---- RY product state ----
    float fl = 1.f;
#pragma unroll
    for (int w = 4; w < 10; ++w)
        fl *= ((lane >> (9 - w)) & 1) ? sth[w] : cth[w];
    float are[16], aim[16];
#pragma unroll
    for (int r = 0; r < 16; ++r) {
        float g = fl;
#pragma unroll
        for (int w = 0; w < 4; ++w)
            g *= ((r >> (3 - w)) & 1) ? sth[w] : cth[w];
        are[r] = g; aim[r] = 0.f;
    }

    // ---- 4 layers ----
    do_layer<0>(gtab, lane, are, aim);
    do_layer<1>(gtab, lane, are, aim);
    do_layer<2>(gtab, lane, are, aim);
    do_layer<3>(gtab, lane, are, aim);

    // ---- Z expectations ----
    float p[16], ptot = 0.f;
#pragma unroll
    for (int r = 0; r < 16; ++r) { p[r] = are[r] * are[r] + aim[r] * aim[r]; ptot += p[r]; }
    float e[NQ];
#pragma unroll
    for (int w = 0; w < 4; ++w) {
        float ss = 0.f;
        const int mask = 1 << (3 - w);
#pragma unroll
        for (int r = 0; r < 16; ++r) if (r & mask) ss += p[r];
        e[w] = ptot - 2.f * ss;
    }
#pragma unroll
    for (int w = 4; w < 10; ++w)
        e[w] = ((lane >> (9 - w)) & 1) ? -ptot : ptot;
#pragma unroll
    for (int w = 0; w < NQ; ++w) e[w] = wave_sum(e[w]);

    // ---- head ----
    float accv = 0.f;
#pragma unroll
    for (int j = 0; j < 2; ++j) {
        int c = lane + 64 * j;
        float d = b3s[c];
#pragma unroll
        for (int k = 0; k < NQ; ++k) d = fmaf(w3s[c * 11 + k], e[k], d);
        d = fmaxf(d, 0.f);
        accv = fmaf(d, w4s[c], accv);
    }
    accv = wave_sum(accv);
    if (lane == 0) out[row] = accv + b4s;
}

extern "C" void kernel_launch(void* const* d_in, const int* in_sizes, int n_in,
                              void* d_out, int out_size, void* d_ws, size_t ws_size,
                              hipStream_t stream) {
    const float* x  = (const float*)d_in[0];
    const float* W1 = (const float*)d_in[1];
    const float* b1 = (const float*)d_in[2];
    const float* W2 = (const float*)d_in[3];
    const float* b2 = (const float*)d_in[4];
    const float* qw = (const float*)d_in[5];
    const float* W3 = (const float*)d_in[6];
    const float* b3 = (const float*)d_in[7];
    const float* W4 = (const float*)d_in[8];
    const float* b4 = (const float*)d_in[9];
    float* gtab = (float*)d_ws;                 // 320 floats
    float* w1t  = (float*)d_ws + 512;           // 32768 floats (16B aligned)
    float* out  = (float*)d_out;

    prep_kernel<<<(INFEAT * HID + 255) / 256, 256, 0, stream>>>(qw, W1, gtab, w1t);
    fused_kernel<<<BATCH / 4, 256, 0, stream>>>(x, w1t, b1, W2, b2, gtab, W3, b3, W4, b4, out);
}

// Round 6
// 283.772 us; speedup vs baseline: 1.1077x; 1.1077x over previous
//
#include <hip/hip_runtime.h>
#include <math.h>

#define BATCH 16384
#define INFEAT 256
#define HID 128
#define NQ 10
#define NL 4

typedef float v2f __attribute__((ext_vector_type(2)));

// ---------- cross-lane xor helper: DPP for 1,2,3,8; ds_swizzle for <32; shfl for 32+ ----------
template<int M>
__device__ __forceinline__ float lxor(float x) {
    if constexpr (M == 0) {
        return x;
    } else if constexpr (M < 4) {
        constexpr int ctrl = (0 ^ M) | ((1 ^ M) << 2) | ((2 ^ M) << 4) | ((3 ^ M) << 6);
        return __int_as_float(__builtin_amdgcn_update_dpp(
            __float_as_int(x), __float_as_int(x), ctrl, 0xF, 0xF, false));
    } else if constexpr (M == 8) {
        return __int_as_float(__builtin_amdgcn_update_dpp(
            __float_as_int(x), __float_as_int(x), 0x128, 0xF, 0xF, false));  // ROW_ROR:8
    } else if constexpr (M < 32) {
        return __int_as_float(__builtin_amdgcn_ds_swizzle(
            __float_as_int(x), (M << 10) | 0x1F));
    } else {
        return __shfl_xor(x, M, 64);
    }
}

// full 64-lane sum — proven lxor ladder (round 3/4). NOTE: do NOT replace the
// 16/32 steps with v_permlane*_swap on two copies of the same value: the tied
// "+v" asm operands can be allocated to the SAME physical register (same SSA
// input), yielding swap(v5,v5) = a permute, not an exchange (round-5 failure).
__device__ __forceinline__ float wave_sum(float v) {
    v += lxor<1>(v); v += lxor<2>(v); v += lxor<8>(v);
    v += lxor<4>(v); v += lxor<16>(v); v += lxor<32>(v);
    return v;
}

// gfx950 VALU cross-lane exchange: swap odd 16/32-rows of a with even rows of b.
// Safe ONLY when a and b are guaranteed-distinct registers (distinct SSA values).
template<int HALF>
__device__ __forceinline__ void swap_pl(float& a, float& b) {
    if constexpr (HALF == 32)
        asm("v_permlane32_swap_b32 %0, %1" : "+v"(a), "+v"(b));
    else
        asm("v_permlane16_swap_b32 %0, %1" : "+v"(a), "+v"(b));
}

// lane-bit Rot gate at 16/32-lane granularity via permlane swaps (pure VALU)
template<int HALF>
__device__ __forceinline__ void lane_gate_pl(const float* __restrict__ g,
                                             float (&are)[16], float (&aim)[16]) {
    const float m00r = g[0], m00i = g[1], m01r = g[2], m01i = g[3];
    const float m10r = g[4], m10i = g[5], m11r = g[6], m11i = g[7];
#pragma unroll
    for (int r0 = 0; r0 < 16; r0 += 2) {
        const int r1 = r0 + 1;
        float Xr = are[r0], Yr = are[r1], Xi = aim[r0], Yi = aim[r1];
        swap_pl<HALF>(Xr, Yr);
        swap_pl<HALF>(Xi, Yi);
        float Pr = m00r * Xr - m00i * Xi + m01r * Yr - m01i * Yi;
        float Pi = m00r * Xi + m00i * Xr + m01r * Yi + m01i * Yr;
        float Qr = m10r * Xr - m10i * Xi + m11r * Yr - m11i * Yi;
        float Qi = m10r * Xi + m10i * Xr + m11r * Yi + m11i * Yr;
        swap_pl<HALF>(Pr, Qr);
        swap_pl<HALF>(Pi, Qi);
        are[r0] = Pr; are[r1] = Qr; aim[r0] = Pi; aim[r1] = Qi;
    }
}

// lane-bit Rot gate via lxor partner (DPP for bits 0,1,3; swizzle for bit 2)
template<int LB>
__device__ __forceinline__ void lane_gate(const float* __restrict__ g, int lane,
                                          float (&are)[16], float (&aim)[16]) {
    const bool side = (lane >> LB) & 1;
    const float cmr = side ? g[6] : g[0];
    const float cmi = side ? g[7] : g[1];
    const float cpr = side ? g[4] : g[2];
    const float cpi = side ? g[5] : g[3];
#pragma unroll
    for (int r = 0; r < 16; ++r) {
        float pr = lxor<(1 << LB)>(are[r]);
        float pi = lxor<(1 << LB)>(aim[r]);
        float nr = cmr * are[r] - cmi * aim[r] + cpr * pr - cpi * pi;
        float ni = cmr * aim[r] + cmi * are[r] + cpr * pi + cpi * pr;
        are[r] = nr; aim[r] = ni;
    }
}

// reg-bit Rot gate (reg-index bit mask)
template<int MASK>
__device__ __forceinline__ void reg_gate(const float* __restrict__ g,
                                         float (&are)[16], float (&aim)[16]) {
    const float m00r = g[0], m00i = g[1], m01r = g[2], m01i = g[3];
    const float m10r = g[4], m10i = g[5], m11r = g[6], m11i = g[7];
#pragma unroll
    for (int r0 = 0; r0 < 16; ++r0) {
        if (r0 & MASK) continue;
        const int r1 = r0 | MASK;
        float a0r = are[r0], a0i = aim[r0], a1r = are[r1], a1i = aim[r1];
        are[r0] = m00r * a0r - m00i * a0i + m01r * a1r - m01i * a1i;
        aim[r0] = m00r * a0i + m00i * a0r + m01r * a1i + m01i * a1r;
        are[r1] = m10r * a0r - m10i * a0i + m11r * a1r - m11i * a1i;
        aim[r1] = m10r * a0i + m10i * a0r + m11r * a1i + m11i * a1r;
    }
}

// ---- compile-time CNOT-ring tables ----
constexpr int rr_src(int rs, int r) {
    int s = r;
    for (int i = 3 - rs; i >= 0; --i) s ^= ((s >> (3 - i)) & 1) << (3 - i - rs);
    return s;
}
constexpr int rl_mask(int rs, int r) {
    int m = 0;
    for (int i = (4 - rs < 0 ? 0 : 4 - rs); i <= 3; ++i)
        if ((r >> (3 - i)) & 1) m |= 1 << (9 - i - rs);
    return m;
}

template<int L>
__device__ __forceinline__ void do_layer(const float* __restrict__ gt, int lane,
                                         float (&are)[16], float (&aim)[16]) {
    constexpr int rs = L + 1;
    const float* __restrict__ gb = gt + L * NQ * 8;
    reg_gate<8>(gb + 0 * 8, are, aim);
    reg_gate<4>(gb + 1 * 8, are, aim);
    reg_gate<2>(gb + 2 * 8, are, aim);
    reg_gate<1>(gb + 3 * 8, are, aim);
    lane_gate_pl<32>(gb + 4 * 8, are, aim);      // bit5
    lane_gate_pl<16>(gb + 5 * 8, are, aim);      // bit4
    lane_gate<3>(gb + 6 * 8, lane, are, aim);    // bit3: DPP row_ror:8
    lane_gate<2>(gb + 7 * 8, lane, are, aim);    // bit2: ds_swizzle
    lane_gate<1>(gb + 8 * 8, lane, are, aim);    // bit1: DPP
    lane_gate<0>(gb + 9 * 8, lane, are, aim);    // bit0: DPP
    // CNOT ring: RR+RL+LL folded into one per-reg bpermute gather
    int y = lane;
#pragma unroll
    for (int i = 9 - rs; i >= 4; --i)
        y ^= ((y >> (9 - i)) & 1) << (9 - i - rs);
    const int base = y << 2;
    {
        float nr[16];
#pragma unroll
        for (int r = 0; r < 16; ++r) {
            const int src = rr_src(rs, r);
            const int am  = rl_mask(rs, r) << 2;
            nr[r] = __int_as_float(__builtin_amdgcn_ds_bpermute(base ^ am, __float_as_int(are[src])));
        }
#pragma unroll
        for (int r = 0; r < 16; ++r) are[r] = nr[r];
    }
    {
        float ni[16];
#pragma unroll
        for (int r = 0; r < 16; ++r) {
            const int src = rr_src(rs, r);
            const int am  = rl_mask(rs, r) << 2;
            ni[r] = __int_as_float(__builtin_amdgcn_ds_bpermute(base ^ am, __float_as_int(aim[src])));
        }
#pragma unroll
        for (int r = 0; r < 16; ++r) aim[r] = ni[r];
    }
    // LR: predicated register-pair swaps
#pragma unroll
    for (int i = 10 - rs; i <= 9; ++i) {
        const bool p = (lane >> (9 - i)) & 1;
        const int tm = 1 << (13 - i - rs);
#pragma unroll
        for (int r = 0; r < 16; ++r) {
            if (!(r & tm)) {
                float v0r = are[r], v1r = are[r | tm];
                are[r] = p ? v1r : v0r;  are[r | tm] = p ? v0r : v1r;
                float v0i = aim[r], v1i = aim[r | tm];
                aim[r] = p ? v1i : v0i;  aim[r | tm] = p ? v0i : v1i;
            }
        }
    }
}

__device__ __forceinline__ float ftanh(float s) {
    float e = __expf(2.f * s);
    return 1.f - 2.f / (e + 1.f);
}

// ---------------- prep: gate table + W1 transpose ----------------
__global__ void prep_kernel(const float* __restrict__ qw, const float* __restrict__ W1,
                            float* __restrict__ gtab, float* __restrict__ w1t) {
    int tid = blockIdx.x * 256 + threadIdx.x;
    if (tid < INFEAT * HID) {
        int c = tid & 127, k = tid >> 7;
        w1t[k * HID + c] = W1[c * INFEAT + k];
    }
    if (blockIdx.x == 0 && threadIdx.x < NL * NQ) {
        int t = threadIdx.x;
        float phi = qw[t * 3 + 0], th = qw[t * 3 + 1], om = qw[t * 3 + 2];
        float c = __cosf(th * 0.5f), s = __sinf(th * 0.5f);
        float a = 0.5f * (phi + om), b = 0.5f * (phi - om);
        float ca = __cosf(a), sa = __sinf(a);
        float cb = __cosf(b), sb = __sinf(b);
        float* g = gtab + t * 8;
        g[0] = ca * c;  g[1] = -sa * c;
        g[2] = -cb * s; g[3] = -sb * s;
        g[4] = cb * s;  g[5] = -sb * s;
        g[6] = ca * c;  g[7] = sa * c;
    }
}

// ---------------- fused kernel: K-split MLP -> circuit -> head ----------------
// Block = 4 waves = 4 batch rows. MLP phase: wave w computes K-slice [64w,64w+64)
// of ALL 4 rows (x via wave-uniform loads, W1 via 64 coalesced float2 loads),
// partials reduced through LDS. Circuit phase: one wave per row, state in registers.
__global__ __launch_bounds__(256) void fused_kernel(
    const float* __restrict__ x, const float* __restrict__ w1t,
    const float* __restrict__ b1, const float* __restrict__ W2,
    const float* __restrict__ b2, const float* __restrict__ gtab,
    const float* __restrict__ W3, const float* __restrict__ b3,
    const float* __restrict__ W4, const float* __restrict__ b4,
    float* __restrict__ out)
{
    __shared__ float w3s[HID * 11];
    __shared__ float b3s[HID], w4s[HID];
    __shared__ float b4s;
    __shared__ v2f hpart[4][4][64];   // [k-slice wave][row][lane(2 cols)]

    const int t = threadIdx.x;
    for (int f = t; f < HID * NQ; f += 256) {
        int c = f / NQ, k = f - c * NQ;
        w3s[c * 11 + k] = W3[f];
    }
    if (t < HID) { b3s[t] = b3[t]; w4s[t] = W4[t]; }
    if (t == 0) b4s = b4[0];

    const int lane = t & 63;
    const int wid = t >> 6;
    const int row0 = blockIdx.x * 4;
    const int ukw = __builtin_amdgcn_readfirstlane(wid);      // wave-uniform k-slice id

    // ---- MLP phase 1: partial h for all 4 rows over k in [64*ukw, 64*ukw+64) ----
    v2f acc[4];
#pragma unroll
    for (int r = 0; r < 4; ++r) acc[r] = (v2f)(0.f);
    const float4* __restrict__ xr0 = (const float4*)(x + (size_t)(row0 + 0) * INFEAT + ukw * 64);
    const float4* __restrict__ xr1 = (const float4*)(x + (size_t)(row0 + 1) * INFEAT + ukw * 64);
    const float4* __restrict__ xr2 = (const float4*)(x + (size_t)(row0 + 2) * INFEAT + ukw * 64);
    const float4* __restrict__ xr3 = (const float4*)(x + (size_t)(row0 + 3) * INFEAT + ukw * 64);
    const float2* __restrict__ w1p = (const float2*)w1t + (size_t)ukw * 64 * 64 + lane;
#pragma unroll 4
    for (int kk4 = 0; kk4 < 16; ++kk4) {
        float4 x0 = xr0[kk4], x1 = xr1[kk4], x2 = xr2[kk4], x3 = xr3[kk4];
        float xk[4][4] = {{x0.x, x0.y, x0.z, x0.w}, {x1.x, x1.y, x1.z, x1.w},
                          {x2.x, x2.y, x2.z, x2.w}, {x3.x, x3.y, x3.z, x3.w}};
#pragma unroll
        for (int j = 0; j < 4; ++j) {
            float2 w = w1p[(kk4 * 4 + j) * 64];
            v2f wv; wv.x = w.x; wv.y = w.y;
#pragma unroll
            for (int r = 0; r < 4; ++r) {
                v2f xb; xb.x = xk[r][j]; xb.y = xk[r][j];
                acc[r] = __builtin_elementwise_fma(xb, wv, acc[r]);
            }
        }
    }
#pragma unroll
    for (int r = 0; r < 4; ++r) hpart[wid][r][lane] = acc[r];
    __syncthreads();

    // ---- MLP phase 2: wave owns its row; sum 4 partials, bias, relu ----
    v2f hs = hpart[0][wid][lane];
    hs += hpart[1][wid][lane];
    hs += hpart[2][wid][lane];
    hs += hpart[3][wid][lane];
    float2 b1v = ((const float2*)b1)[lane];
    float h0 = fmaxf(hs.x + b1v.x, 0.f);
    float h1 = fmaxf(hs.y + b1v.y, 0.f);

    const int row = row0 + wid;

    // ---- angles = tanh(h@W2^T + b2), wave-reduced ----
    float cth[NQ], sth[NQ];
#pragma unroll
    for (int w = 0; w < NQ; ++w) {
        float2 w2v = ((const float2*)(W2 + (size_t)w * HID))[lane];
        float aw = wave_sum(fmaf(h0, w2v.x, h1 * w2v.y)) + b2[w];
        float th = ftanh(aw) * 0.5f;
        cth[w] = __cosf(th); sth[w] = __sinf(th);
    }

    // ---- RY product state ----
    float fl = 1.f;
#pragma unroll
    for (int w = 4; w < 10; ++w)
        fl *= ((lane >> (9 - w)) & 1) ? sth[w] : cth[w];
    float are[16], aim[16];
#pragma unroll
    for (int r = 0; r < 16; ++r) {
        float g = fl;
#pragma unroll
        for (int w = 0; w < 4; ++w)
            g *= ((r >> (3 - w)) & 1) ? sth[w] : cth[w];
        are[r] = g; aim[r] = 0.f;
    }

    // ---- 4 layers ----
    do_layer<0>(gtab, lane, are, aim);
    do_layer<1>(gtab, lane, are, aim);
    do_layer<2>(gtab, lane, are, aim);
    do_layer<3>(gtab, lane, are, aim);

    // ---- Z expectations ----
    float p[16], ptot = 0.f;
#pragma unroll
    for (int r = 0; r < 16; ++r) { p[r] = are[r] * are[r] + aim[r] * aim[r]; ptot += p[r]; }
    float e[NQ];
#pragma unroll
    for (int w = 0; w < 4; ++w) {
        float ss = 0.f;
        const int mask = 1 << (3 - w);
#pragma unroll
        for (int r = 0; r < 16; ++r) if (r & mask) ss += p[r];
        e[w] = ptot - 2.f * ss;
    }
#pragma unroll
    for (int w = 4; w < 10; ++w)
        e[w] = ((lane >> (9 - w)) & 1) ? -ptot : ptot;
#pragma unroll
    for (int w = 0; w < NQ; ++w) e[w] = wave_sum(e[w]);

    // ---- head ----
    float accv = 0.f;
#pragma unroll
    for (int j = 0; j < 2; ++j) {
        int c = lane + 64 * j;
        float d = b3s[c];
#pragma unroll
        for (int k = 0; k < NQ; ++k) d = fmaf(w3s[c * 11 + k], e[k], d);
        d = fmaxf(d, 0.f);
        accv = fmaf(d, w4s[c], accv);
    }
    accv = wave_sum(accv);
    if (lane == 0) out[row] = accv + b4s;
}

extern "C" void kernel_launch(void* const* d_in, const int* in_sizes, int n_in,
                              void* d_out, int out_size, void* d_ws, size_t ws_size,
                              hipStream_t stream) {
    const float* x  = (const float*)d_in[0];
    const float* W1 = (const float*)d_in[1];
    const float* b1 = (const float*)d_in[2];
    const float* W2 = (const float*)d_in[3];
    const float* b2 = (const float*)d_in[4];
    const float* qw = (const float*)d_in[5];
    const float* W3 = (const float*)d_in[6];
    const float* b3 = (const float*)d_in[7];
    const float* W4 = (const float*)d_in[8];
    const float* b4 = (const float*)d_in[9];
    float* gtab = (float*)d_ws;                 // 320 floats
    float* w1t  = (float*)d_ws + 512;           // 32768 floats (16B aligned)
    float* out  = (float*)d_out;

    prep_kernel<<<(INFEAT * HID + 255) / 256, 256, 0, stream>>>(qw, W1, gtab, w1t);
    fused_kernel<<<BATCH / 4, 256, 0, stream>>>(x, w1t, b1, W2, b2, gtab, W3, b3, W4, b4, out);
}

// Round 7
// 243.555 us; speedup vs baseline: 1.2907x; 1.1651x over previous
//
#include <hip/hip_runtime.h>
#include <math.h>

#define BATCH 16384
#define INFEAT 256
#define HID 128
#define NQ 10
#define NL 4

typedef float v2f __attribute__((ext_vector_type(2)));

// ---------- cross-lane xor helper: DPP for 1,2,3,8; ds_swizzle for <32; shfl for 32+ ----------
template<int M>
__device__ __forceinline__ float lxor(float x) {
    if constexpr (M == 0) {
        return x;
    } else if constexpr (M < 4) {
        constexpr int ctrl = (0 ^ M) | ((1 ^ M) << 2) | ((2 ^ M) << 4) | ((3 ^ M) << 6);
        return __int_as_float(__builtin_amdgcn_update_dpp(
            __float_as_int(x), __float_as_int(x), ctrl, 0xF, 0xF, false));
    } else if constexpr (M == 8) {
        return __int_as_float(__builtin_amdgcn_update_dpp(
            __float_as_int(x), __float_as_int(x), 0x128, 0xF, 0xF, false));  // ROW_ROR:8
    } else if constexpr (M < 32) {
        return __int_as_float(__builtin_amdgcn_ds_swizzle(
            __float_as_int(x), (M << 10) | 0x1F));
    } else {
        return __shfl_xor(x, M, 64);
    }
}

// full 64-lane sum — proven lxor ladder. (permlane-swap on two copies of the SAME
// SSA value mis-allocates to one register — round-5 failure; keep this form.)
__device__ __forceinline__ float wave_sum(float v) {
    v += lxor<1>(v); v += lxor<2>(v); v += lxor<8>(v);
    v += lxor<4>(v); v += lxor<16>(v); v += lxor<32>(v);
    return v;
}

// gfx950 VALU cross-lane exchange; a and b MUST be distinct SSA values.
template<int HALF>
__device__ __forceinline__ void swap_pl(float& a, float& b) {
    if constexpr (HALF == 32)
        asm("v_permlane32_swap_b32 %0, %1" : "+v"(a), "+v"(b));
    else
        asm("v_permlane16_swap_b32 %0, %1" : "+v"(a), "+v"(b));
}

// ---- state: v2f AR[8], AI[8]; element e = 2k+h; qubit w(0..3) <-> e-bit(3-w);
// ---- qubits 4..9 <-> lane bits 5..0.

// element accessors (e compile-time after unroll)
__device__ __forceinline__ float getv(const v2f (&A)[8], int e) {
    return (e & 1) ? A[e >> 1].y : A[e >> 1].x;
}
__device__ __forceinline__ void setv(v2f (&A)[8], int e, float v) {
    if (e & 1) A[e >> 1].y = v; else A[e >> 1].x = v;
}

// reg-bit Rot gate for qubits 0..2 (k-mask KM): pure packed math
template<int KM>
__device__ __forceinline__ void reg_gate_pk(const float* __restrict__ g,
                                            v2f (&AR)[8], v2f (&AI)[8]) {
    const v2f m00r=(v2f)(g[0]), m00i=(v2f)(g[1]), m01r=(v2f)(g[2]), m01i=(v2f)(g[3]);
    const v2f m10r=(v2f)(g[4]), m10i=(v2f)(g[5]), m11r=(v2f)(g[6]), m11i=(v2f)(g[7]);
#pragma unroll
    for (int k0 = 0; k0 < 8; ++k0) {
        if (k0 & KM) continue;
        const int k1 = k0 | KM;
        v2f A0 = AR[k0], I0 = AI[k0], A1 = AR[k1], I1 = AI[k1];
        AR[k0] = m00r*A0 - m00i*I0 + m01r*A1 - m01i*I1;
        AI[k0] = m00r*I0 + m00i*A0 + m01r*I1 + m01i*A1;
        AR[k1] = m10r*A0 - m10i*I0 + m11r*A1 - m11i*I1;
        AI[k1] = m10r*I0 + m10i*A0 + m11r*I1 + m11i*A1;
    }
}

// qubit-3 gate (mixes the two halves of each v2f) via interleaved coefficient pairs
__device__ __forceinline__ void reg_gate_q3(const float* __restrict__ g,
                                            v2f (&AR)[8], v2f (&AI)[8]) {
    const v2f P0 = *(const v2f*)(g + 8);   // (m00r, m10r)
    const v2f P1 = *(const v2f*)(g + 10);  // (m00i, m10i)
    const v2f P2 = *(const v2f*)(g + 12);  // (m01r, m11r)
    const v2f P3 = *(const v2f*)(g + 14);  // (m01i, m11i)
#pragma unroll
    for (int k = 0; k < 8; ++k) {
        v2f Axx = __builtin_shufflevector(AR[k], AR[k], 0, 0);
        v2f Ayy = __builtin_shufflevector(AR[k], AR[k], 1, 1);
        v2f Ixx = __builtin_shufflevector(AI[k], AI[k], 0, 0);
        v2f Iyy = __builtin_shufflevector(AI[k], AI[k], 1, 1);
        AR[k] = P0*Axx - P1*Ixx + P2*Ayy - P3*Iyy;
        AI[k] = P0*Ixx + P1*Axx + P2*Iyy + P3*Ayy;
    }
}

// lane-bit Rot gate bits 0..3 via lxor partner, packed arithmetic
template<int LB>
__device__ __forceinline__ void lane_gate_pk(const float* __restrict__ g, int lane,
                                             v2f (&AR)[8], v2f (&AI)[8]) {
    const bool side = (lane >> LB) & 1;
    const float cmr_s = side ? g[6] : g[0];
    const float cmi_s = side ? g[7] : g[1];
    const float cpr_s = side ? g[4] : g[2];
    const float cpi_s = side ? g[5] : g[3];
    const v2f cmr=(v2f)(cmr_s), cmi=(v2f)(cmi_s), cpr=(v2f)(cpr_s), cpi=(v2f)(cpi_s);
#pragma unroll
    for (int k = 0; k < 8; ++k) {
        v2f PR, PI;
        PR.x = lxor<(1 << LB)>(AR[k].x); PR.y = lxor<(1 << LB)>(AR[k].y);
        PI.x = lxor<(1 << LB)>(AI[k].x); PI.y = lxor<(1 << LB)>(AI[k].y);
        v2f NR = cmr*AR[k] - cmi*AI[k] + cpr*PR - cpi*PI;
        v2f NI = cmr*AI[k] + cmi*AR[k] + cpr*PI + cpi*PR;
        AR[k] = NR; AI[k] = NI;
    }
}

// lane-bit Rot gate bits 4/5 via permlane swaps, packed arithmetic (uniform coeffs)
template<int HALF>
__device__ __forceinline__ void lane_gate_pl_pk(const float* __restrict__ g,
                                                v2f (&AR)[8], v2f (&AI)[8]) {
    const v2f m00r=(v2f)(g[0]), m00i=(v2f)(g[1]), m01r=(v2f)(g[2]), m01i=(v2f)(g[3]);
    const v2f m10r=(v2f)(g[4]), m10i=(v2f)(g[5]), m11r=(v2f)(g[6]), m11i=(v2f)(g[7]);
#pragma unroll
    for (int k0 = 0; k0 < 8; k0 += 2) {
        const int k1 = k0 + 1;
        float Xr0=AR[k0].x, Xr1=AR[k0].y, Yr0=AR[k1].x, Yr1=AR[k1].y;
        float Xi0=AI[k0].x, Xi1=AI[k0].y, Yi0=AI[k1].x, Yi1=AI[k1].y;
        swap_pl<HALF>(Xr0, Yr0); swap_pl<HALF>(Xr1, Yr1);
        swap_pl<HALF>(Xi0, Yi0); swap_pl<HALF>(Xi1, Yi1);
        v2f Xr = {Xr0, Xr1}, Yr = {Yr0, Yr1}, Xi = {Xi0, Xi1}, Yi = {Yi0, Yi1};
        v2f Pr = m00r*Xr - m00i*Xi + m01r*Yr - m01i*Yi;
        v2f Pi = m00r*Xi + m00i*Xr + m01r*Yi + m01i*Yr;
        v2f Qr = m10r*Xr - m10i*Xi + m11r*Yr - m11i*Yi;
        v2f Qi = m10r*Xi + m10i*Xr + m11r*Yi + m11i*Yr;
        float pr0=Pr.x, pr1=Pr.y, qr0=Qr.x, qr1=Qr.y;
        float pi0=Pi.x, pi1=Pi.y, qi0=Qi.x, qi1=Qi.y;
        swap_pl<HALF>(pr0, qr0); swap_pl<HALF>(pr1, qr1);
        swap_pl<HALF>(pi0, qi0); swap_pl<HALF>(pi1, qi1);
        AR[k0].x=pr0; AR[k0].y=pr1; AR[k1].x=qr0; AR[k1].y=qr1;
        AI[k0].x=pi0; AI[k0].y=pi1; AI[k1].x=qi0; AI[k1].y=qi1;
    }
}

// ---- compile-time CNOT-ring tables (element index e, 4 bits) ----
constexpr int rr_src(int rs, int e) {
    int s = e;
    for (int i = 3 - rs; i >= 0; --i) s ^= ((s >> (3 - i)) & 1) << (3 - i - rs);
    return s;
}
constexpr int rl_mask(int rs, int e) {
    int m = 0;
    for (int i = (4 - rs < 0 ? 0 : 4 - rs); i <= 3; ++i)
        if ((e >> (3 - i)) & 1) m |= 1 << (9 - i - rs);
    return m;
}

template<int L>
__device__ __forceinline__ void do_layer(const float* __restrict__ gt, int lane,
                                         v2f (&AR)[8], v2f (&AI)[8]) {
    constexpr int rs = L + 1;
    const float* __restrict__ gb = gt + L * NQ * 16;
    reg_gate_pk<4>(gb + 0 * 16, AR, AI);   // qubit0: e-mask 8
    reg_gate_pk<2>(gb + 1 * 16, AR, AI);   // qubit1: e-mask 4
    reg_gate_pk<1>(gb + 2 * 16, AR, AI);   // qubit2: e-mask 2
    reg_gate_q3  (gb + 3 * 16, AR, AI);    // qubit3: e-mask 1
    lane_gate_pl_pk<32>(gb + 4 * 16, AR, AI);
    lane_gate_pl_pk<16>(gb + 5 * 16, AR, AI);
    lane_gate_pk<3>(gb + 6 * 16, lane, AR, AI);
    lane_gate_pk<2>(gb + 7 * 16, lane, AR, AI);
    lane_gate_pk<1>(gb + 8 * 16, lane, AR, AI);
    lane_gate_pk<0>(gb + 9 * 16, lane, AR, AI);
    // ---- CNOT ring: RR+RL+LL folded into one per-element bpermute gather ----
    int y = lane;
#pragma unroll
    for (int i = 9 - rs; i >= 4; --i)
        y ^= ((y >> (9 - i)) & 1) << (9 - i - rs);
    const int base = y << 2;
    {
        float nr[16], ni[16];
#pragma unroll
        for (int e = 0; e < 16; ++e) {
            const int src = rr_src(rs, e);
            const int am  = rl_mask(rs, e) << 2;
            nr[e] = __int_as_float(__builtin_amdgcn_ds_bpermute(base ^ am, __float_as_int(getv(AR, src))));
            ni[e] = __int_as_float(__builtin_amdgcn_ds_bpermute(base ^ am, __float_as_int(getv(AI, src))));
        }
#pragma unroll
        for (int k = 0; k < 8; ++k) {
            AR[k].x = nr[2 * k]; AR[k].y = nr[2 * k + 1];
            AI[k].x = ni[2 * k]; AI[k].y = ni[2 * k + 1];
        }
    }
    // LR: predicated element-pair swaps
#pragma unroll
    for (int i = 10 - rs; i <= 9; ++i) {
        const bool p = (lane >> (9 - i)) & 1;
        const int tm = 1 << (13 - i - rs);
#pragma unroll
        for (int e = 0; e < 16; ++e) {
            if (!(e & tm)) {
                const int e1 = e | tm;
                float v0r = getv(AR, e), v1r = getv(AR, e1);
                setv(AR, e, p ? v1r : v0r); setv(AR, e1, p ? v0r : v1r);
                float v0i = getv(AI, e), v1i = getv(AI, e1);
                setv(AI, e, p ? v1i : v0i); setv(AI, e1, p ? v0i : v1i);
            }
        }
    }
}

__device__ __forceinline__ float ftanh(float s) {
    float e = __expf(2.f * s);
    return 1.f - 2.f / (e + 1.f);
}

// ---------------- prep: gate table (16 floats/gate, incl q3 pair layout) + W1 transpose ----------------
__global__ void prep_kernel(const float* __restrict__ qw, const float* __restrict__ W1,
                            float* __restrict__ gtab, float* __restrict__ w1t) {
    int tid = blockIdx.x * 256 + threadIdx.x;
    if (tid < INFEAT * HID) {
        int c = tid & 127, k = tid >> 7;
        w1t[k * HID + c] = W1[c * INFEAT + k];
    }
    if (blockIdx.x == 0 && threadIdx.x < NL * NQ) {
        int t = threadIdx.x;
        float phi = qw[t * 3 + 0], th = qw[t * 3 + 1], om = qw[t * 3 + 2];
        float c = __cosf(th * 0.5f), s = __sinf(th * 0.5f);
        float a = 0.5f * (phi + om), b = 0.5f * (phi - om);
        float ca = __cosf(a), sa = __sinf(a);
        float cb = __cosf(b), sb = __sinf(b);
        float* g = gtab + t * 16;
        g[0] = ca * c;  g[1] = -sa * c;   // m00
        g[2] = -cb * s; g[3] = -sb * s;   // m01
        g[4] = cb * s;  g[5] = -sb * s;   // m10
        g[6] = ca * c;  g[7] = sa * c;    // m11
        // q3 interleaved pairs: (m00r,m10r),(m00i,m10i),(m01r,m11r),(m01i,m11i)
        g[8]  = ca * c;  g[9]  = cb * s;
        g[10] = -sa * c; g[11] = -sb * s;
        g[12] = -cb * s; g[13] = ca * c;
        g[14] = -sb * s; g[15] = sa * c;
    }
}

// ---------------- fused kernel: K-split MLP -> circuit -> head ----------------
__global__ __launch_bounds__(256) void fused_kernel(
    const float* __restrict__ x, const float* __restrict__ w1t,
    const float* __restrict__ b1, const float* __restrict__ W2,
    const float* __restrict__ b2, const float* __restrict__ gtab,
    const float* __restrict__ W3, const float* __restrict__ b3,
    const float* __restrict__ W4, const float* __restrict__ b4,
    float* __restrict__ out)
{
    __shared__ float w3s[HID * 11];
    __shared__ float b3s[HID], w4s[HID];
    __shared__ float b4s;
    __shared__ v2f hpart[4][4][64];   // [k-slice wave][row][lane(2 cols)]

    const int t = threadIdx.x;
    for (int f = t; f < HID * NQ; f += 256) {
        int c = f / NQ, k = f - c * NQ;
        w3s[c * 11 + k] = W3[f];
    }
    if (t < HID) { b3s[t] = b3[t]; w4s[t] = W4[t]; }
    if (t == 0) b4s = b4[0];

    const int lane = t & 63;
    const int wid = t >> 6;
    const int row0 = blockIdx.x * 4;
    const int ukw = __builtin_amdgcn_readfirstlane(wid);

    // ---- MLP phase 1: partial h for all 4 rows over k-slice ----
    v2f acc[4];
#pragma unroll
    for (int r = 0; r < 4; ++r) acc[r] = (v2f)(0.f);
    const float4* __restrict__ xr0 = (const float4*)(x + (size_t)(row0 + 0) * INFEAT + ukw * 64);
    const float4* __restrict__ xr1 = (const float4*)(x + (size_t)(row0 + 1) * INFEAT + ukw * 64);
    const float4* __restrict__ xr2 = (const float4*)(x + (size_t)(row0 + 2) * INFEAT + ukw * 64);
    const float4* __restrict__ xr3 = (const float4*)(x + (size_t)(row0 + 3) * INFEAT + ukw * 64);
    const float2* __restrict__ w1p = (const float2*)w1t + (size_t)ukw * 64 * 64 + lane;
#pragma unroll 4
    for (int kk4 = 0; kk4 < 16; ++kk4) {
        float4 x0 = xr0[kk4], x1 = xr1[kk4], x2 = xr2[kk4], x3 = xr3[kk4];
        float xk[4][4] = {{x0.x, x0.y, x0.z, x0.w}, {x1.x, x1.y, x1.z, x1.w},
                          {x2.x, x2.y, x2.z, x2.w}, {x3.x, x3.y, x3.z, x3.w}};
#pragma unroll
        for (int j = 0; j < 4; ++j) {
            float2 w = w1p[(kk4 * 4 + j) * 64];
            v2f wv; wv.x = w.x; wv.y = w.y;
#pragma unroll
            for (int r = 0; r < 4; ++r) {
                v2f xb; xb.x = xk[r][j]; xb.y = xk[r][j];
                acc[r] = __builtin_elementwise_fma(xb, wv, acc[r]);
            }
        }
    }
#pragma unroll
    for (int r = 0; r < 4; ++r) hpart[wid][r][lane] = acc[r];
    __syncthreads();

    // ---- MLP phase 2 ----
    v2f hs = hpart[0][wid][lane];
    hs += hpart[1][wid][lane];
    hs += hpart[2][wid][lane];
    hs += hpart[3][wid][lane];
    float2 b1v = ((const float2*)b1)[lane];
    float h0 = fmaxf(hs.x + b1v.x, 0.f);
    float h1 = fmaxf(hs.y + b1v.y, 0.f);

    const int row = row0 + wid;

    // ---- angles = tanh(h@W2^T + b2) ----
    float cth[NQ], sth[NQ];
#pragma unroll
    for (int w = 0; w < NQ; ++w) {
        float2 w2v = ((const float2*)(W2 + (size_t)w * HID))[lane];
        float aw = wave_sum(fmaf(h0, w2v.x, h1 * w2v.y)) + b2[w];
        float th = ftanh(aw) * 0.5f;
        cth[w] = __cosf(th); sth[w] = __sinf(th);
    }

    // ---- RY product state ----
    float fl = 1.f;
#pragma unroll
    for (int w = 4; w < 10; ++w)
        fl *= ((lane >> (9 - w)) & 1) ? sth[w] : cth[w];
    v2f AR[8], AI[8];
    {
        float ev[16];
#pragma unroll
        for (int e = 0; e < 16; ++e) {
            float g = fl;
#pragma unroll
            for (int w = 0; w < 4; ++w)
                g *= ((e >> (3 - w)) & 1) ? sth[w] : cth[w];
            ev[e] = g;
        }
#pragma unroll
        for (int k = 0; k < 8; ++k) {
            AR[k].x = ev[2 * k]; AR[k].y = ev[2 * k + 1];
            AI[k] = (v2f)(0.f);
        }
    }

    // ---- 4 layers ----
    do_layer<0>(gtab, lane, AR, AI);
    do_layer<1>(gtab, lane, AR, AI);
    do_layer<2>(gtab, lane, AR, AI);
    do_layer<3>(gtab, lane, AR, AI);

    // ---- Z expectations ----
    v2f Pk[8];
#pragma unroll
    for (int k = 0; k < 8; ++k) Pk[k] = AR[k] * AR[k] + AI[k] * AI[k];
    v2f S = Pk[0] + Pk[1] + Pk[2] + Pk[3] + Pk[4] + Pk[5] + Pk[6] + Pk[7];
    float ptot = S.x + S.y;
    v2f Sq0 = Pk[4] + Pk[5] + Pk[6] + Pk[7];
    v2f Sq1 = Pk[2] + Pk[3] + Pk[6] + Pk[7];
    v2f Sq2 = Pk[1] + Pk[3] + Pk[5] + Pk[7];
    float es0 = wave_sum(ptot - 2.f * (Sq0.x + Sq0.y));
    float es1 = wave_sum(ptot - 2.f * (Sq1.x + Sq1.y));
    float es2 = wave_sum(ptot - 2.f * (Sq2.x + Sq2.y));
    float es3 = wave_sum(ptot - 2.f * S.y);
    // lane-qubit expectations via one Walsh-Hadamard butterfly on ptot:
    // final lane m holds sum_l (-1)^{<m,l>} ptot_l; single-bit m = e[qubit 9-log2(m)]
    float Wv = ptot;
    {
        float p;
        p = lxor<1>(Wv);  Wv = (lane & 1)  ? p - Wv : Wv + p;
        p = lxor<2>(Wv);  Wv = (lane & 2)  ? p - Wv : Wv + p;
        p = lxor<4>(Wv);  Wv = (lane & 4)  ? p - Wv : Wv + p;
        p = lxor<8>(Wv);  Wv = (lane & 8)  ? p - Wv : Wv + p;
        p = lxor<16>(Wv); Wv = (lane & 16) ? p - Wv : Wv + p;
        p = lxor<32>(Wv); Wv = (lane & 32) ? p - Wv : Wv + p;
    }
    const int wvi = __float_as_int(Wv);
    float es[NQ];
    es[0] = es0; es[1] = es1; es[2] = es2; es[3] = es3;
    es[4] = __int_as_float(__builtin_amdgcn_readlane(wvi, 32));
    es[5] = __int_as_float(__builtin_amdgcn_readlane(wvi, 16));
    es[6] = __int_as_float(__builtin_amdgcn_readlane(wvi, 8));
    es[7] = __int_as_float(__builtin_amdgcn_readlane(wvi, 4));
    es[8] = __int_as_float(__builtin_amdgcn_readlane(wvi, 2));
    es[9] = __int_as_float(__builtin_amdgcn_readlane(wvi, 1));

    // ---- head ----
    float accv = 0.f;
#pragma unroll
    for (int j = 0; j < 2; ++j) {
        int c = lane + 64 * j;
        float d = b3s[c];
#pragma unroll
        for (int k = 0; k < NQ; ++k) d = fmaf(w3s[c * 11 + k], es[k], d);
        d = fmaxf(d, 0.f);
        accv = fmaf(d, w4s[c], accv);
    }
    accv = wave_sum(accv);
    if (lane == 0) out[row] = accv + b4s;
}

extern "C" void kernel_launch(void* const* d_in, const int* in_sizes, int n_in,
                              void* d_out, int out_size, void* d_ws, size_t ws_size,
                              hipStream_t stream) {
    const float* x  = (const float*)d_in[0];
    const float* W1 = (const float*)d_in[1];
    const float* b1 = (const float*)d_in[2];
    const float* W2 = (const float*)d_in[3];
    const float* b2 = (const float*)d_in[4];
    const float* qw = (const float*)d_in[5];
    const float* W3 = (const float*)d_in[6];
    const float* b3 = (const float*)d_in[7];
    const float* W4 = (const float*)d_in[8];
    const float* b4 = (const float*)d_in[9];
    float* gtab = (float*)d_ws;                 // 640 floats (16/gate)
    float* w1t  = (float*)d_ws + 1024;          // 32768 floats
    float* out  = (float*)d_out;

    prep_kernel<<<(INFEAT * HID + 255) / 256, 256, 0, stream>>>(qw, W1, gtab, w1t);
    fused_kernel<<<BATCH / 4, 256, 0, stream>>>(x, w1t, b1, W2, b2, gtab, W3, b3, W4, b4, out);
}